// Round 10
// baseline (266.587 us; speedup 1.0000x reference)
//
#include <hip/hip_runtime.h>

typedef short short8 __attribute__((ext_vector_type(8)));
typedef short short4v __attribute__((ext_vector_type(4)));
typedef float float4v __attribute__((ext_vector_type(4)));
typedef int int4v __attribute__((ext_vector_type(4)));
typedef unsigned int uint2v __attribute__((ext_vector_type(2)));
typedef unsigned int uint4v __attribute__((ext_vector_type(4)));
typedef unsigned short ushort_t;

#define INV_EXT (1.0f / 0.048f)
#define HN 32
#define KK 15
#define CIN 64
#define COUT 64
#define PB 16        /* points per block */
#define ROWE 1032    /* wtS row stride in elements: 1024 + 8 (16B pad) */
#define NSLOT 16     /* stats atomic slots */

// round-half-up bf16 (max rel err same scale as RNE; no tie logic)
__device__ inline ushort_t rh_bf16(float f) {
    return (ushort_t)((__float_as_uint(f) + 0x8000u) >> 16);
}
// pack two floats into two bf16 in one u32 (lo = a, hi = b)
__device__ inline unsigned pk_bf16(float a, float b) {
    unsigned ua = __float_as_uint(a) + 0x8000u;
    unsigned ub = __float_as_uint(b) + 0x8000u;
    return (ua >> 16) | (ub & 0xffff0000u);
}

union Frag8 { short8 s; uint4v u; };

// ================= K1: main KPConv (fused slotted stats) =================
// wtS logical kd-slot j = c*16 + k' (k' padded to 16). Row stride ROWE elems
// (+16B pad) -> phase-3 reads are affine (imm offsets) and near conflict-free.
template <bool XB>
__global__ __launch_bounds__(256, 4)
void kpconv_main(const float* __restrict__ q_pts,
                 const float* __restrict__ s_pts,
                 const int*   __restrict__ inds,
                 const float* __restrict__ x,
                 const float* __restrict__ kpts,
                 const ushort_t* __restrict__ W3,   // [128 j-octets][64 d][8] bf16
                 const ushort_t* __restrict__ xb,   // [N][64] bf16, channel-permuted
                 const float4v* __restrict__ sp4,   // [N] padded s_pts (16B)
                 float* __restrict__ out,
                 float* __restrict__ sums, int N)
{
    __shared__ int indS[PB * HN];                     // 2 KB
    __shared__ __align__(16) short wtS[PB * ROWE];    // 33 KB

    const int t = threadIdx.x;
    const int n0 = blockIdx.x * PB;
    const int lane = t & 63;
    const int wid = t >> 6;
    const int l15 = lane & 15;
    const int q = lane >> 4;

    // ---- phase 0: copy this block's 512 neighbor indices to LDS ----
    {
        int pi = t;
        int n = n0 + (pi >> 5);
        indS[pi] = (n < N) ? inds[n0 * HN + pi] : 0;
        pi = t + 256;
        n = n0 + (pi >> 5);
        indS[pi] = (n < N) ? inds[n0 * HN + pi] : 0;
    }
    __syncthreads();

    // ---- indices into registers: 2 x ds_read_b128 per point (broadcast) ----
    int4v idx8[4][2];
#pragma unroll
    for (int i = 0; i < 4; ++i) {
        int base = (wid * 4 + i) * HN + q * 8;
        idx8[i][0] = *(int4v*)&indS[base];
        idx8[i][1] = *(int4v*)&indS[base + 4];
    }

    // ---- issue ALL phase-2 xb gathers early (hide under phase-1 VALU) ----
    short4v L[4][8];
    if constexpr (XB) {
#pragma unroll
        for (int i = 0; i < 4; ++i)
#pragma unroll
            for (int j = 0; j < 8; ++j) {
                int idx = idx8[i][j >> 2][j & 3];
                L[i][j] = *(const short4v*)(xb + (size_t)idx * CIN + l15 * 4);
            }
    }

    // ---- phase 1: influence weights -> A-fragments (per-lane sp4 gather) ----
    // lane holds A[m=k'=l15][k=h=q*8+j] = w[h][k']
    int kidx = l15 < KK ? l15 : 0;
    float kx = kpts[kidx * 3 + 0];
    float ky = kpts[kidx * 3 + 1];
    float kz = kpts[kidx * 3 + 2];
    if (l15 >= KK) { kx = 3e4f; ky = 3e4f; kz = 3e4f; }  // pad k' -> w==0
    Frag8 afrag[4];
#pragma unroll
    for (int i = 0; i < 4; ++i) {
        int nc = n0 + wid * 4 + i; if (nc >= N) nc = N - 1;
        // fold query point + kernel point into one constant per (i, lane)
        float qkx = q_pts[nc * 3 + 0] + kx;
        float qky = q_pts[nc * 3 + 1] + ky;
        float qkz = q_pts[nc * 3 + 2] + kz;
        float w[8];
#pragma unroll
        for (int j = 0; j < 8; ++j) {
            int idx = idx8[i][j >> 2][j & 3];
            float dx, dy, dz;
            if constexpr (XB) {
                float4v sp = sp4[idx];
                dx = sp[0] - qkx; dy = sp[1] - qky; dz = sp[2] - qkz;
            } else {
                const float* sp = s_pts + (size_t)idx * 3;
                dx = sp[0] - qkx; dy = sp[1] - qky; dz = sp[2] - qkz;
            }
            float d = __builtin_amdgcn_sqrtf(fmaf(dx, dx, fmaf(dy, dy, dz * dz)));
            w[j] = fmaxf(fmaf(d, -INV_EXT, 1.0f), 0.0f);
        }
#pragma unroll
        for (int jj = 0; jj < 4; ++jj)
            afrag[i].u[jj] = pk_bf16(w[2 * jj], w[2 * jj + 1]);
    }

    // ---- phase 2: per wave, 4 points: wt[k'][c] = w^T @ feat via MFMA ----
#pragma unroll
    for (int i = 0; i < 4; ++i) {
        int p = wid * 4 + i;
        const float* rpf[8];
        if constexpr (!XB) {
#pragma unroll
            for (int j = 0; j < 8; ++j)
                rpf[j] = x + (size_t)idx8[i][j >> 2][j & 3] * CIN;
        }
#pragma unroll
        for (int ct = 0; ct < 4; ++ct) {
            short8 b;
#pragma unroll
            for (int j = 0; j < 8; ++j) {
                if constexpr (XB) b[j] = L[i][j][ct];
                else              b[j] = (short)rh_bf16(rpf[j][ct * 16 + l15]);
            }
            float4v acc = {0.f, 0.f, 0.f, 0.f};
            acc = __builtin_amdgcn_mfma_f32_16x16x32_bf16(afrag[i].s, b, acc, 0, 0, 0);
            // D row m=k'=q*4+r, col c=ct*16+l15 -> j = c*16 + (q*4+r)
            uint2v v2;
            v2[0] = pk_bf16(acc[0], acc[1]);
            v2[1] = pk_bf16(acc[2], acc[3]);
            *(uint2v*)&wtS[p * ROWE + (ct * 16 + l15) * 16 + q * 4] = v2;
        }
    }
    __syncthreads();

    // ---- phase 3: OUT[16p x 64d] = wt[16p x 1024j] @ W3[1024j x 64d] ----
    {
        const int d0 = wid * 16;
        float4v acc = {0.f, 0.f, 0.f, 0.f};
        // A: row l15, j = s*32+q*8 -> el = l15*ROWE + s*32 + q*8 (imm in s)
        const short* wa = &wtS[l15 * ROWE + q * 8];
        // B: j-octet (s*4+q), col d0+l15: contiguous 16B, coalesced
        const ushort_t* wb = W3 + (size_t)q * 512 + (d0 + l15) * 8;
#pragma unroll 8
        for (int s = 0; s < 32; ++s) {
            short8 a = *(const short8*)(wa + s * 32);
            short8 b = *(const short8*)(wb + (size_t)s * 2048);
            acc = __builtin_amdgcn_mfma_f32_16x16x32_bf16(a, b, acc, 0, 0, 0);
        }
        // store + fused per-channel stats (slotted atomics)
        float s1 = 0.f, s2 = 0.f;
#pragma unroll
        for (int r = 0; r < 4; ++r) {
            int p = q * 4 + r;
            int n = n0 + p;
            float v = acc[r];
            if (n < N) { out[n * COUT + d0 + l15] = v; s1 += v; s2 += v * v; }
        }
        s1 += __shfl_xor(s1, 16); s2 += __shfl_xor(s2, 16);
        s1 += __shfl_xor(s1, 32); s2 += __shfl_xor(s2, 32);
        if (q == 0) {
            int slot = blockIdx.x & (NSLOT - 1);
            atomicAdd(&sums[slot * 128 + d0 + l15], s1);
            atomicAdd(&sums[slot * 128 + 64 + d0 + l15], s2);
        }
    }
}

// ====== K0: prep (zero stats, W->W3 plain j-map, x->xb permuted, s_pts->sp4) ======
template <bool XB>
__global__ void prep_kernel(const float* __restrict__ W, const float* __restrict__ x,
                            const float* __restrict__ s_pts,
                            float* sums, ushort_t* W3, ushort_t* xb,
                            float4v* sp4, int N)
{
    long gt = (long)blockIdx.x * 256 + threadIdx.x;
    long stride = (long)gridDim.x * 256;
    if (gt < NSLOT * 128) sums[gt] = 0.f;
    for (long i = gt; i < COUT * 1024; i += stride) {
        int d = (int)((i >> 3) & 63);
        int j = (int)(((i >> 9) << 3) | (i & 7));  // kd-slot: j = c*16 + k'
        int k = j & 15, c = j >> 4;
        W3[i] = (k < KK) ? rh_bf16(W[(k * CIN + c) * COUT + d]) : (ushort_t)0;
    }
    if constexpr (XB) {
        // xb[n][tt*4+ct] = bf16(x[n][ct*16+tt]); read AND write coalesced
        long nq = (long)N * 16;
        for (long iq = gt; iq < nq; iq += stride) {
            long n = iq >> 4; int tt = (int)(iq & 15);
            const float* xp = x + n * 64;
            uint2v v;
            v[0] = pk_bf16(xp[tt], xp[tt + 16]);
            v[1] = pk_bf16(xp[tt + 32], xp[tt + 48]);
            *(uint2v*)(xb + n * 64 + tt * 4) = v;
        }
        // sp4: 16B-padded copy of s_pts for single-instruction gathers
        for (long n = gt; n < N; n += stride) {
            float4v v;
            v[0] = s_pts[n * 3 + 0];
            v[1] = s_pts[n * 3 + 1];
            v[2] = s_pts[n * 3 + 2];
            v[3] = 0.f;
            sp4[n] = v;
        }
    }
}

// ================= K2: reduce slots + instance-norm + LeakyReLU ========
__global__ void norm_kernel(float* out, const float* __restrict__ sums, int N)
{
    __shared__ float meanS[64], invS[64];
    int t = threadIdx.x;
    if (t < 64) {
        float s1 = 0.f, s2 = 0.f;
#pragma unroll
        for (int sl = 0; sl < NSLOT; ++sl) {
            s1 += sums[sl * 128 + t];
            s2 += sums[sl * 128 + 64 + t];
        }
        float invN = 1.0f / (float)N;
        float mean = s1 * invN;
        float var = fmaxf(s2 * invN - mean * mean, 0.f);
        meanS[t] = mean;
        invS[t] = rsqrtf(var + 1e-5f);
    }
    __syncthreads();
    long total = (long)N * 64 / 4;
    for (long i = (long)blockIdx.x * blockDim.x + t; i < total;
         i += (long)gridDim.x * blockDim.x) {
        int cb = (int)((i * 4) & 63);
        float4v v = *(float4v*)&out[i * 4];
#pragma unroll
        for (int j = 0; j < 4; ++j) {
            float val = (v[j] - meanS[cb + j]) * invS[cb + j];
            v[j] = val >= 0.f ? val : 0.1f * val;
        }
        *(float4v*)&out[i * 4] = v;
    }
}

extern "C" void kernel_launch(void* const* d_in, const int* in_sizes, int n_in,
                              void* d_out, int out_size, void* d_ws, size_t ws_size,
                              hipStream_t stream)
{
    const float* q  = (const float*)d_in[0];
    const float* s  = (const float*)d_in[1];
    const int* inds = (const int*)d_in[2];
    const float* x  = (const float*)d_in[3];
    const float* kp = (const float*)d_in[4];
    const float* W  = (const float*)d_in[5];
    float* out = (float*)d_out;
    int N = in_sizes[0] / 3;

    float* sums  = (float*)d_ws;                                   // 8 KB
    ushort_t* W3 = (ushort_t*)((char*)d_ws + 8192);                // 128 KB
    ushort_t* xb = (ushort_t*)((char*)d_ws + 8192 + 131072);       // N*128 B
    float4v* sp4 = (float4v*)((char*)d_ws + 8192 + 131072 + (size_t)N * 128);
    bool useXB = ws_size >= 8192 + 131072 + (size_t)N * 128 + (size_t)N * 16;

    int nblk = (N + PB - 1) / PB;
    if (useXB) {
        prep_kernel<true ><<<512, 256, 0, stream>>>(W, x, s, sums, W3, xb, sp4, N);
        kpconv_main<true ><<<nblk, 256, 0, stream>>>(q, s, inds, x, kp, W3, xb, sp4, out, sums, N);
    } else {
        prep_kernel<false><<<512, 256, 0, stream>>>(W, x, s, sums, W3, xb, sp4, N);
        kpconv_main<false><<<nblk, 256, 0, stream>>>(q, s, inds, x, kp, W3, xb, sp4, out, sums, N);
    }
    norm_kernel<<<1024, 256, 0, stream>>>(out, sums, N);
}

// Round 11
// 180.711 us; speedup vs baseline: 1.4752x; 1.4752x over previous
//
#include <hip/hip_runtime.h>

typedef short short8 __attribute__((ext_vector_type(8)));
typedef short short4v __attribute__((ext_vector_type(4)));
typedef float float4v __attribute__((ext_vector_type(4)));
typedef int int4v __attribute__((ext_vector_type(4)));
typedef unsigned int uint2v __attribute__((ext_vector_type(2)));
typedef unsigned int uint4v __attribute__((ext_vector_type(4)));
typedef unsigned short ushort_t;

#define INV_EXT (1.0f / 0.048f)
#define HN 32
#define KK 15
#define CIN 64
#define COUT 64
#define PB 16      /* points per block */
#define KDIM 1024  /* padded 16 k' * 64 c, order defined by j-map */
#define NSLOT 16   /* stats atomic slots */

// round-half-up bf16 (max rel err same scale as RNE; no tie logic -> 1 add)
__device__ inline ushort_t rh_bf16(float f) {
    return (ushort_t)((__float_as_uint(f) + 0x8000u) >> 16);
}
// pack two floats into two bf16 in one u32 (lo = a, hi = b)
__device__ inline unsigned pk_bf16(float a, float b) {
    unsigned ua = __float_as_uint(a) + 0x8000u;
    unsigned ub = __float_as_uint(b) + 0x8000u;
    return (ua >> 16) | (ub & 0xffff0000u);
}

union Frag8 { short8 s; uint4v u; };

// wtS element index: row p, logical kd-slot j (0..1023). 16B granule (8 elems)
// XOR-swizzled by p so phase-3 reads (p = lane&15) spread across banks.
__device__ inline int wtJ(int p, int j) {
    return p * KDIM + ((((j >> 3) ^ (p & 7)) << 3) | (j & 7));
}

// ================= K1: main KPConv (fused slotted stats) =================
template <bool XB>
__global__ __launch_bounds__(256, 4)
void kpconv_main(const float* __restrict__ q_pts,
                 const float* __restrict__ s_pts,
                 const int*   __restrict__ inds,
                 const float* __restrict__ x,
                 const float* __restrict__ kpts,
                 const ushort_t* __restrict__ W3,   // [128 kd-octets][64 d][8] bf16
                 const ushort_t* __restrict__ xb,   // [N][64] bf16, channel-permuted
                 float* __restrict__ out,
                 float* __restrict__ sums, int N)
{
    __shared__ float nX[PB * HN], nY[PB * HN], nZ[PB * HN]; // 6 KB
    __shared__ int indS[PB * HN];                           // 2 KB
    __shared__ __align__(16) short wtS[PB * KDIM];          // 32 KB

    const int t = threadIdx.x;
    const int n0 = blockIdx.x * PB;
    const int lane = t & 63;
    const int wid = t >> 6;
    const int l15 = lane & 15;
    const int q = lane >> 4;

    // ---- pre-step: neighbor diffs + indices (block-wide) ----
    for (int it = 0; it < 2; ++it) {
        int pi = t + it * 256;          // (p,h)
        int p = pi >> 5, h = pi & 31;
        int n = n0 + p;
        float dx = 1e9f, dy = 1e9f, dz = 1e9f; int idx = 0;
        if (n < N) {
            idx = inds[n * HN + h];
            dx = s_pts[idx * 3 + 0] - q_pts[n * 3 + 0];
            dy = s_pts[idx * 3 + 1] - q_pts[n * 3 + 1];
            dz = s_pts[idx * 3 + 2] - q_pts[n * 3 + 2];
        }
        indS[pi] = idx;
        nX[pi] = dx; nY[pi] = dy; nZ[pi] = dz;
    }
    __syncthreads();

    // ---- indices into registers: 2 x ds_read_b128 per point (broadcast) ----
    int4v idx8[4][2];
#pragma unroll
    for (int i = 0; i < 4; ++i) {
        int base = (wid * 4 + i) * HN + q * 8;
        idx8[i][0] = *(int4v*)&indS[base];
        idx8[i][1] = *(int4v*)&indS[base + 4];
    }

    // ---- phase-2 xb gathers (compiler schedules/sinks as it sees fit) ----
    short4v L[4][8];
    if constexpr (XB) {
#pragma unroll
        for (int i = 0; i < 4; ++i)
#pragma unroll
            for (int j = 0; j < 8; ++j) {
                int idx = idx8[i][j >> 2][j & 3];
                L[i][j] = *(const short4v*)(xb + (size_t)idx * CIN + l15 * 4);
            }
    }

    // ---- phase 1: influence weights straight into A-fragment registers ----
    // A-frag (16x16x32): lane holds A[m=k'=l15][k=h=q*8+j] = w[h][k']
    int kidx = l15 < KK ? l15 : 0;
    float kx = kpts[kidx * 3 + 0];
    float ky = kpts[kidx * 3 + 1];
    float kz = kpts[kidx * 3 + 2];
    // pad kernel point (l15 >= KK): push it 3e4 away -> w clamps to 0.
    if (l15 >= KK) { kx = 3e4f; ky = 3e4f; kz = 3e4f; }
    Frag8 afrag[4];
#pragma unroll
    for (int i = 0; i < 4; ++i) {
        int p = wid * 4 + i;
        int base = p * HN + q * 8;       // 16B-aligned
        float4v x0 = *(float4v*)&nX[base], x1 = *(float4v*)&nX[base + 4];
        float4v y0 = *(float4v*)&nY[base], y1 = *(float4v*)&nY[base + 4];
        float4v z0 = *(float4v*)&nZ[base], z1 = *(float4v*)&nZ[base + 4];
        float w[8];
#pragma unroll
        for (int j = 0; j < 8; ++j) {
            float dx = (j < 4 ? x0[j & 3] : x1[j & 3]) - kx;
            float dy = (j < 4 ? y0[j & 3] : y1[j & 3]) - ky;
            float dz = (j < 4 ? z0[j & 3] : z1[j & 3]) - kz;
            float d = __builtin_amdgcn_sqrtf(fmaf(dx, dx, fmaf(dy, dy, dz * dz)));
            w[j] = fmaxf(fmaf(d, -INV_EXT, 1.0f), 0.0f);
        }
#pragma unroll
        for (int jj = 0; jj < 4; ++jj)
            afrag[i].u[jj] = pk_bf16(w[2 * jj], w[2 * jj + 1]);
    }

    // ---- phase 2: per wave, 4 points: wt[k'][c] = w^T @ feat via MFMA ----
#pragma unroll
    for (int i = 0; i < 4; ++i) {
        int p = wid * 4 + i;
        const float* rpf[8];
        if constexpr (!XB) {
#pragma unroll
            for (int j = 0; j < 8; ++j)
                rpf[j] = x + (size_t)idx8[i][j >> 2][j & 3] * CIN;
        }
#pragma unroll
        for (int ct = 0; ct < 4; ++ct) {
            short8 b;
#pragma unroll
            for (int j = 0; j < 8; ++j) {
                if constexpr (XB) b[j] = L[i][j][ct];
                else              b[j] = (short)rh_bf16(rpf[j][ct * 16 + l15]);
            }
            float4v acc = {0.f, 0.f, 0.f, 0.f};
            acc = __builtin_amdgcn_mfma_f32_16x16x32_bf16(afrag[i].s, b, acc, 0, 0, 0);
            // D row m = k' = q*4+r, col n = c = ct*16+l15.
            // kd-slot j(k',c) = quad*4 + r, quad = l15 + 16*(q^ct) + 64*ct
            uint2v v2;
            v2[0] = pk_bf16(acc[0], acc[1]);
            v2[1] = pk_bf16(acc[2], acc[3]);
            int quad = l15 + 16 * (q ^ ct) + 64 * ct;
            *(uint2v*)&wtS[wtJ(p, quad * 4)] = v2;
        }
    }
    __syncthreads();

    // ---- phase 3: OUT[16p x 64d] = wt[16p x 1024j] @ W3[1024j x 64d] ----
    {
        const int d0 = wid * 16;
        float4v acc = {0.f, 0.f, 0.f, 0.f};
        // B-frag: lane needs W3 j-slots s*32+q*8+(0..7) at col d0+l15 ->
        // octet (s*4+q), contiguous 16B: fully coalesced dwordx4
        const ushort_t* wb = W3 + (size_t)q * 512 + (d0 + l15) * 8;
#pragma unroll 8
        for (int s = 0; s < 32; ++s) {
            short8 a = *(short8*)&wtS[wtJ(l15, s * 32 + q * 8)];
            short8 b = *(const short8*)(wb + (size_t)s * 2048);
            acc = __builtin_amdgcn_mfma_f32_16x16x32_bf16(a, b, acc, 0, 0, 0);
        }
        // store + fused per-channel stats (slotted atomics)
        float s1 = 0.f, s2 = 0.f;
#pragma unroll
        for (int r = 0; r < 4; ++r) {
            int p = q * 4 + r;
            int n = n0 + p;
            float v = acc[r];
            if (n < N) { out[n * COUT + d0 + l15] = v; s1 += v; s2 += v * v; }
        }
        s1 += __shfl_xor(s1, 16); s2 += __shfl_xor(s2, 16);
        s1 += __shfl_xor(s1, 32); s2 += __shfl_xor(s2, 32);
        if (q == 0) {
            int slot = blockIdx.x & (NSLOT - 1);
            atomicAdd(&sums[slot * 128 + d0 + l15], s1);
            atomicAdd(&sums[slot * 128 + 64 + d0 + l15], s2);
        }
    }
}

// ================= K0: prep (zero stats, W->W3 blocked layout, x->xb permuted) ===
template <bool XB>
__global__ void prep_kernel(const float* __restrict__ W, const float* __restrict__ x,
                            float* sums, ushort_t* W3, ushort_t* xb, int N)
{
    long gt = (long)blockIdx.x * 256 + threadIdx.x;
    long stride = (long)gridDim.x * 256;
    if (gt < NSLOT * 128) sums[gt] = 0.f;
    for (long i = gt; i < COUT * KDIM; i += stride) {
        int d = (int)((i >> 3) & 63);
        int j = (int)(((i >> 9) << 3) | (i & 7));  // kd-slot
        int quad = j >> 2, r = j & 3;
        int l15 = quad & 15, e = (quad >> 4) & 3, ct = quad >> 6;
        int k = (e ^ ct) * 4 + r, c = ct * 16 + l15;
        W3[i] = (k < KK) ? rh_bf16(W[(k * CIN + c) * COUT + d]) : (ushort_t)0;
    }
    if constexpr (XB) {
        // xb[n][tt*4+ct] = bf16(x[n][ct*16+tt]); read AND write coalesced
        long nq = (long)N * 16;
        for (long iq = gt; iq < nq; iq += stride) {
            long n = iq >> 4; int tt = (int)(iq & 15);
            const float* xp = x + n * 64;
            uint2v v;
            v[0] = pk_bf16(xp[tt], xp[tt + 16]);
            v[1] = pk_bf16(xp[tt + 32], xp[tt + 48]);
            *(uint2v*)(xb + n * 64 + tt * 4) = v;
        }
    }
}

// ================= K2: reduce slots + instance-norm + LeakyReLU ========
__global__ void norm_kernel(float* out, const float* __restrict__ sums, int N)
{
    __shared__ float meanS[64], invS[64];
    int t = threadIdx.x;
    if (t < 64) {
        float s1 = 0.f, s2 = 0.f;
#pragma unroll
        for (int sl = 0; sl < NSLOT; ++sl) {
            s1 += sums[sl * 128 + t];
            s2 += sums[sl * 128 + 64 + t];
        }
        float invN = 1.0f / (float)N;
        float mean = s1 * invN;
        float var = fmaxf(s2 * invN - mean * mean, 0.f);
        meanS[t] = mean;
        invS[t] = rsqrtf(var + 1e-5f);
    }
    __syncthreads();
    long total = (long)N * 64 / 4;
    for (long i = (long)blockIdx.x * blockDim.x + t; i < total;
         i += (long)gridDim.x * blockDim.x) {
        int cb = (int)((i * 4) & 63);
        float4v v = *(float4v*)&out[i * 4];
#pragma unroll
        for (int j = 0; j < 4; ++j) {
            float val = (v[j] - meanS[cb + j]) * invS[cb + j];
            v[j] = val >= 0.f ? val : 0.1f * val;
        }
        *(float4v*)&out[i * 4] = v;
    }
}

extern "C" void kernel_launch(void* const* d_in, const int* in_sizes, int n_in,
                              void* d_out, int out_size, void* d_ws, size_t ws_size,
                              hipStream_t stream)
{
    const float* q  = (const float*)d_in[0];
    const float* s  = (const float*)d_in[1];
    const int* inds = (const int*)d_in[2];
    const float* x  = (const float*)d_in[3];
    const float* kp = (const float*)d_in[4];
    const float* W  = (const float*)d_in[5];
    float* out = (float*)d_out;
    int N = in_sizes[0] / 3;

    float* sums  = (float*)d_ws;                                // 8 KB
    ushort_t* W3 = (ushort_t*)((char*)d_ws + 8192);             // 128 KB
    ushort_t* xb = (ushort_t*)((char*)d_ws + 8192 + 131072);
    bool useXB = ws_size >= 8192 + 131072 + (size_t)N * CIN * 2;

    int nblk = (N + PB - 1) / PB;
    if (useXB) {
        prep_kernel<true ><<<1024, 256, 0, stream>>>(W, x, sums, W3, xb, N);
        kpconv_main<true ><<<nblk, 256, 0, stream>>>(q, s, inds, x, kp, W3, xb, out, sums, N);
    } else {
        prep_kernel<false><<<1024, 256, 0, stream>>>(W, x, sums, W3, xb, N);
        kpconv_main<false><<<nblk, 256, 0, stream>>>(q, s, inds, x, kp, W3, xb, out, sums, N);
    }
    norm_kernel<<<2048, 256, 0, stream>>>(out, sums, N);
}